// Round 11
// baseline (428.486 us; speedup 1.0000x reference)
//
#include <hip/hip_runtime.h>
#include <stdint.h>

// LSTM autoencoder B=32768 T=30 I=4 H=64 L=32, fp32 in/out.
// v11 = v10 (341us) restructured as a LAYER-PIPELINED producer/consumer:
// 16 waves/block (1024 thr), 8 pairs x 16 batches (BPB=128, grid 256).
// Front wave (role 0) runs enc1/dec1 for t=s; back wave (role 1) runs
// enc2/dec2 for t=s-1, h1/h3 passed through a double-buffered LDS A-tile,
// one __syncthreads per step. Total work per SIMD unchanged vs v10, but
// 4 waves/SIMD (vs 2) overlap trans/LDS/MFMA latency. 1-term bf16 MFMA
// everywhere (absmax pinned at the fp32 floor 9.77e-4 since v4).
// Front MFMA processed in two nt-halves to keep accs at 32 VGPRs (cap 128).
// Layouts (HW-verified): C/D col=lane&15,row=(lane>>4)*4+reg [m89];
// A m=lane&15,k=(lane>>4)*8+j [m120]; B n=lane&15,k=(lane>>4)*8+j.

typedef unsigned short u16;
typedef unsigned int u32;
typedef __attribute__((ext_vector_type(8))) short bf16x8;
typedef __attribute__((ext_vector_type(4))) short s16x4;
typedef __attribute__((ext_vector_type(4))) float f32x4;

#define BATCH 32768
#define TT 30
#define IN 4
#define WAVES 16
#define BLOCKT (WAVES * 64)   // 1024
#define MB 16
#define NPAIR 8
#define BPB (NPAIR * MB)      // 128 batches/block -> grid 256, 1 round

// ---- LDS word (u32/float) offsets ----
#define WREG 18432
// enc phase
#define O_WHH1HI 0       // 8192 words (32 frags)
#define O_W1FOLD 8192    // 4096 words (16 frags: x+bias fold tile)
#define O_WIH2HI 12288   // 4096
#define O_WHH2HI 16384   // 2048 -> 18432
// dec phase (same region)
#define O_WHH3HI 0       // 8192
#define O_WIH3HI 8192    // 4096
#define O_WIH4HI 12288   // 512
#define O_W4HHF  12800   // 64 fp32 -> 12864

#define NBIAS 400   // b2[128] @0 | b3[256] @128 | b4[16] @384
// per-pair floats: h1/h3 dbuf 1024 (2 x 512) | h2 256 | xfold/gbuf 256 | h4 64
#define PBUF 1600
#define SMEM_WORDS (WREG + NBIAS + NPAIR * PBUF)   // 31632
#define SMEM_BYTES (SMEM_WORDS * 4)                // 126528 <= 163840

#define WB() __builtin_amdgcn_wave_barrier()
#define MFMA(a, b, c) __builtin_amdgcn_mfma_f32_16x16x32_bf16((a), (b), (c), 0, 0, 0)

__device__ __forceinline__ u16 f2bf(float f) {   // RNE fp32->bf16
    u32 u = __float_as_uint(f);
    u += 0x7fffu + ((u >> 16) & 1u);
    return (u16)(u >> 16);
}
__device__ __forceinline__ float bf2f(u16 v) { return __uint_as_float(((u32)v) << 16); }
__device__ __forceinline__ float sigf(float x) {
    return __builtin_amdgcn_rcpf(1.f + __expf(-x));
}
__device__ __forceinline__ float tanh_(float x) {
    const float t = __expf(2.f * x);
    return fmaf(-2.f, __builtin_amdgcn_rcpf(t + 1.f), 1.f);
}

// Stage fp32 W[N][K] -> bf16 hi, B-fragment order:
// u16 idx = ((nt*KT + kt)*64 + l)*8 + j, n = nt*16+(l&15), k = kt*32+((l>>4)<<3)+j
template <int KT>
__device__ __forceinline__ void stageBh(u16* hi, const float* src, int N, int tid) {
    const int K = KT * 32;
    const int total = N * K;
    for (int idx = tid; idx < total; idx += BLOCKT) {
        const int j = idx & 7;
        const int l = (idx >> 3) & 63;
        const int pair = idx >> 9;
        const int kt = pair & (KT - 1);
        const int nt = pair / KT;
        const int n = (nt << 4) | (l & 15);
        const int k = (kt << 5) + ((l >> 4) << 3) + j;
        hi[idx] = f2bf(src[n * K + k]);
    }
}

__device__ __forceinline__ f32x4 splat4(float b) {
    f32x4 v = {b, b, b, b};
    return v;
}

__global__ __launch_bounds__(BLOCKT, 4) void lstm_ae(
    const float* __restrict__ x,
    const float* __restrict__ w1ih, const float* __restrict__ w1hh,
    const float* __restrict__ b1i, const float* __restrict__ b1h,
    const float* __restrict__ w2ih, const float* __restrict__ w2hh,
    const float* __restrict__ b2i, const float* __restrict__ b2h,
    const float* __restrict__ w3ih, const float* __restrict__ w3hh,
    const float* __restrict__ b3i, const float* __restrict__ b3h,
    const float* __restrict__ w4ih, const float* __restrict__ w4hh,
    const float* __restrict__ b4i, const float* __restrict__ b4h,
    float* __restrict__ out) {
    extern __shared__ float smem[];
    float* W = smem;
    float* biasF = smem + WREG;        // b2[128] b3[256] b4[16]
    float* bufs = biasF + NBIAS;

    const int tid = threadIdx.x;
    const int wave = tid >> 6, lane = tid & 63;
    const int pair = wave & 7, role = wave >> 3;   // 0=front(enc1/dec1) 1=back(enc2/dec2)
    const int col = lane & 15, quad = lane >> 4;

    float* pb = bufs + pair * PBUF;
    u16* h1d = (u16*)pb;               // 2048 u16: dbuf parity p at p*1024
    u16* h2b = (u16*)(pb + 1024);      // 512 u16 (h2/latent, 1 k-tile)
    u16* xfold = (u16*)(pb + 1280);    // 512 u16 (front, enc) / gbuf (back, dec)
    float* gbuf = pb + 1280;           // [16 batch][16 gate] fp32 (back, dec)
    float* bufH4 = pb + 1536;          // [16 batch][4] fp32 (back, dec)

    const int b0w = blockIdx.x * BPB + pair * MB;

    // ---------------- stage ENCODER weights + biases ----------------
    stageBh<2>((u16*)(W + O_WHH1HI), w1hh, 256, tid);
    stageBh<2>((u16*)(W + O_WIH2HI), w2ih, 128, tid);
    stageBh<1>((u16*)(W + O_WHH2HI), w2hh, 128, tid);
    // fold tile: B kt per nt: k0-3 whi | k4-7 whi | k8-11 wlo | k12 bias_hi | k13 bias_lo
    {
        u16* F = (u16*)(W + O_W1FOLD);
        for (int idx = tid; idx < 16 * 512; idx += BLOCKT) {
            const int nt = idx >> 9;
            const int rem = idx & 511;
            const int l = rem >> 3;
            const int j = rem & 7;
            const int q = l >> 4;
            const int n = (nt << 4) | (l & 15);
            u16 v = 0;
            if (q == 0) {
                v = f2bf(w1ih[n * 4 + (j & 3)]);
            } else if (q == 1) {
                if (j < 4) {
                    const float w = w1ih[n * 4 + j];
                    v = f2bf(w - bf2f(f2bf(w)));
                } else if (j == 4) {
                    v = f2bf(b1i[n] + b1h[n]);
                } else if (j == 5) {
                    const float b = b1i[n] + b1h[n];
                    v = f2bf(b - bf2f(f2bf(b)));
                }
            }
            F[idx] = v;
        }
    }
    for (int i = tid; i < 128; i += BLOCKT) biasF[i] = b2i[i] + b2h[i];
    for (int i = tid; i < 256; i += BLOCKT) biasF[128 + i] = b3i[i] + b3h[i];
    for (int i = tid; i < 16; i += BLOCKT) biasF[384 + i] = b4i[i] + b4h[i];
    // zero pair buffers (front: dbuf+xfold, back: h2+h4), set xfold 1.0 slots
    {
        u32* z = (u32*)pb;
        if (role == 0) {
            for (int i = lane; i < 1024; i += 64) z[i] = 0u;
            for (int i = lane; i < 256; i += 64) z[1280 + i] = 0u;
        } else {
            for (int i = lane; i < 256; i += 64) z[1024 + i] = 0u;
            if (lane < 64) bufH4[lane] = 0.f;
        }
    }
    WB();
    if (role == 0 && quad == 1) {
        xfold[lane * 8 + 4] = (u16)0x3F80;   // bf16(1.0) pairs bias_hi
        xfold[lane * 8 + 5] = (u16)0x3F80;   // bf16(1.0) pairs bias_lo
    }
    __syncthreads();

    const u16* Whh1hi = (const u16*)(W + O_WHH1HI);
    const u16* W1fold = (const u16*)(W + O_W1FOLD);
    const u16* Wih2hi = (const u16*)(W + O_WIH2HI);
    const u16* Whh2hi = (const u16*)(W + O_WHH2HI);

    // ================= encoder (pipelined) =================
    float c1[4][4];   // front: [q][r]
    float c2[2][4];   // back
#pragma unroll
    for (int q = 0; q < 4; ++q)
#pragma unroll
        for (int r = 0; r < 4; ++r) c1[q][r] = 0.f;
#pragma unroll
    for (int q = 0; q < 2; ++q)
#pragma unroll
        for (int r = 0; r < 4; ++r) c2[q][r] = 0.f;
    float bias2r[8];
#pragma unroll
    for (int nt = 0; nt < 8; ++nt) bias2r[nt] = biasF[nt * 16 + col];

    const f32x4 zf = {0.f, 0.f, 0.f, 0.f};
    float4 xcur;
    if (role == 0)
        xcur = *reinterpret_cast<const float4*>(x + ((size_t)(b0w + col) * TT + 0) * IN);

    for (int s = 0; s <= TT; ++s) {
        if (role == 0) {
            if (s < TT) {
                // ---- front: enc1 for t=s ----
                {   // write x into the fold A-tile
                    const u16 xh0 = f2bf(xcur.x), xh1 = f2bf(xcur.y);
                    const u16 xh2 = f2bf(xcur.z), xh3 = f2bf(xcur.w);
                    if (quad == 0) {
                        bf16x8 v;
                        v[0] = (short)xh0; v[1] = (short)xh1; v[2] = (short)xh2; v[3] = (short)xh3;
                        v[4] = (short)f2bf(xcur.x - bf2f(xh0));
                        v[5] = (short)f2bf(xcur.y - bf2f(xh1));
                        v[6] = (short)f2bf(xcur.z - bf2f(xh2));
                        v[7] = (short)f2bf(xcur.w - bf2f(xh3));
                        *reinterpret_cast<bf16x8*>(xfold + lane * 8) = v;
                    } else if (quad == 1) {
                        s16x4 v;
                        v[0] = (short)xh0; v[1] = (short)xh1; v[2] = (short)xh2; v[3] = (short)xh3;
                        *reinterpret_cast<s16x4*>(xfold + lane * 8) = v;
                    }
                }
                WB();
                {   // prefetch next x
                    const int tn = (s + 1 < TT) ? s + 1 : s;
                    xcur = *reinterpret_cast<const float4*>(
                        x + ((size_t)(b0w + col) * TT + tn) * IN);
                }
                const u16* hprev = h1d + (((s + 1) & 1) << 10);   // h1[s-1]
                u16* hout = h1d + ((s & 1) << 10);                // h1[s]
                const bf16x8 a1h0 = *reinterpret_cast<const bf16x8*>(hprev + lane * 8);
                const bf16x8 a1h1 = *reinterpret_cast<const bf16x8*>(hprev + (64 + lane) * 8);
                const bf16x8 a1x = *reinterpret_cast<const bf16x8*>(xfold + lane * 8);
#pragma unroll
                for (int half = 0; half < 2; ++half) {
                    f32x4 acc[8];
#pragma unroll
                    for (int i = 0; i < 8; ++i) {
                        const int q = half * 2 + (i >> 2);
                        const int nt = (i & 3) * 4 + q;
                        const bf16x8 bx = *reinterpret_cast<const bf16x8*>(W1fold + (nt * 64 + lane) * 8);
                        const bf16x8 bh0 = *reinterpret_cast<const bf16x8*>(Whh1hi + ((nt * 2 + 0) * 64 + lane) * 8);
                        const bf16x8 bh1 = *reinterpret_cast<const bf16x8*>(Whh1hi + ((nt * 2 + 1) * 64 + lane) * 8);
                        f32x4 a = MFMA(a1x, bx, zf);
                        a = MFMA(a1h0, bh0, a);
                        a = MFMA(a1h1, bh1, a);
                        acc[i] = a;
                    }
#pragma unroll
                    for (int qi = 0; qi < 2; ++qi) {
                        const int q = half * 2 + qi;
                        const int kt = q >> 1;
                        const int lup = ((((q & 1) << 1) + (col >> 3)) << 4);
                        const int j = col & 7;
#pragma unroll
                        for (int r = 0; r < 4; ++r) {
                            const int m = quad * 4 + r;
                            const float iv = sigf(acc[qi * 4 + 0][r]);
                            const float fv = sigf(acc[qi * 4 + 1][r]);
                            const float gv = tanh_(acc[qi * 4 + 2][r]);
                            const float ov = sigf(acc[qi * 4 + 3][r]);
                            c1[q][r] = fv * c1[q][r] + iv * gv;
                            const float h = ov * tanh_(c1[q][r]);
                            hout[(kt * 64 + m + lup) * 8 + j] = f2bf(h);
                        }
                    }
                }
            }
        } else {
            if (s >= 1) {
                // ---- back: enc2 for t=s-1 ----
                const u16* hprev = h1d + (((s + 1) & 1) << 10);   // h1[s-1]
                const bf16x8 a1h0 = *reinterpret_cast<const bf16x8*>(hprev + lane * 8);
                const bf16x8 a1h1 = *reinterpret_cast<const bf16x8*>(hprev + (64 + lane) * 8);
                const bf16x8 a2h = *reinterpret_cast<const bf16x8*>(h2b + lane * 8);
                f32x4 acc2[8];
#pragma unroll
                for (int nt = 0; nt < 8; ++nt) {
                    const bf16x8 bh0 = *reinterpret_cast<const bf16x8*>(Wih2hi + ((nt * 2 + 0) * 64 + lane) * 8);
                    const bf16x8 bh1 = *reinterpret_cast<const bf16x8*>(Wih2hi + ((nt * 2 + 1) * 64 + lane) * 8);
                    const bf16x8 ch = *reinterpret_cast<const bf16x8*>(Whh2hi + (nt * 64 + lane) * 8);
                    f32x4 a = splat4(bias2r[nt]);
                    a = MFMA(a1h0, bh0, a);
                    a = MFMA(a1h1, bh1, a);
                    a = MFMA(a2h, ch, a);
                    acc2[nt] = a;
                }
                WB();   // a2h read before h2 overwrite
#pragma unroll
                for (int q = 0; q < 2; ++q) {
                    const int lup = (((q << 1) + (col >> 3)) << 4);
                    const int j = col & 7;
#pragma unroll
                    for (int r = 0; r < 4; ++r) {
                        const int m = quad * 4 + r;
                        const float iv = sigf(acc2[q][r]);
                        const float fv = sigf(acc2[2 + q][r]);
                        const float gv = tanh_(acc2[4 + q][r]);
                        const float ov = sigf(acc2[6 + q][r]);
                        c2[q][r] = fv * c2[q][r] + iv * gv;
                        const float h = ov * tanh_(c2[q][r]);
                        h2b[(m + lup) * 8 + j] = f2bf(h);
                    }
                }
            }
        }
        __syncthreads();
    }
    // h2b holds the latent.

    // ---------------- re-stage DECODER weights ----------------
    stageBh<2>((u16*)(W + O_WHH3HI), w3hh, 256, tid);
    stageBh<1>((u16*)(W + O_WIH3HI), w3ih, 256, tid);
    stageBh<2>((u16*)(W + O_WIH4HI), w4ih, 16, tid);
    for (int i = tid; i < 64; i += BLOCKT) W[O_W4HHF + i] = w4hh[i];
    // zero h3 dbuf (front) + h4 (back)
    if (role == 0) {
        u32* z = (u32*)pb;
        for (int i = lane; i < 1024; i += 64) z[i] = 0u;
    } else {
        if (lane < 64) bufH4[lane] = 0.f;
    }
    __syncthreads();

    const u16* Whh3hi = (const u16*)(W + O_WHH3HI);
    const u16* Wih3hi = (const u16*)(W + O_WIH3HI);
    const u16* Wih4hi = (const u16*)(W + O_WIH4HI);
    const float* W4hhF = W + O_W4HHF;

    // ================= decoder (pipelined) =================
    float c3[4][4], bias3r[16];
    float c4 = 0.f, bias4r = 0.f;
    bf16x8 aLh;
    if (role == 0) {
#pragma unroll
        for (int q = 0; q < 4; ++q)
#pragma unroll
            for (int r = 0; r < 4; ++r) c3[q][r] = 0.f;
#pragma unroll
        for (int nt = 0; nt < 16; ++nt) bias3r[nt] = biasF[128 + nt * 16 + col];
        aLh = *reinterpret_cast<const bf16x8*>(h2b + lane * 8);   // latent A-frag
    } else {
        bias4r = biasF[384 + col];
    }
    const int u4 = lane & 3, mb = lane >> 2;   // back dec2 epilogue task

    for (int s = 0; s <= TT; ++s) {
        if (role == 0) {
            if (s < TT) {
                // ---- front: dec1 for t=s ----
                const u16* hprev = h1d + (((s + 1) & 1) << 10);   // h3[s-1]
                u16* hout = h1d + ((s & 1) << 10);                // h3[s]
                const bf16x8 a3h0 = *reinterpret_cast<const bf16x8*>(hprev + lane * 8);
                const bf16x8 a3h1 = *reinterpret_cast<const bf16x8*>(hprev + (64 + lane) * 8);
#pragma unroll
                for (int half = 0; half < 2; ++half) {
                    f32x4 acc[8];
#pragma unroll
                    for (int i = 0; i < 8; ++i) {
                        const int q = half * 2 + (i >> 2);
                        const int nt = (i & 3) * 4 + q;
                        const bf16x8 bL = *reinterpret_cast<const bf16x8*>(Wih3hi + (nt * 64 + lane) * 8);
                        const bf16x8 bh0 = *reinterpret_cast<const bf16x8*>(Whh3hi + ((nt * 2 + 0) * 64 + lane) * 8);
                        const bf16x8 bh1 = *reinterpret_cast<const bf16x8*>(Whh3hi + ((nt * 2 + 1) * 64 + lane) * 8);
                        f32x4 a = MFMA(aLh, bL, splat4(bias3r[nt]));
                        a = MFMA(a3h0, bh0, a);
                        a = MFMA(a3h1, bh1, a);
                        acc[i] = a;
                    }
#pragma unroll
                    for (int qi = 0; qi < 2; ++qi) {
                        const int q = half * 2 + qi;
                        const int kt = q >> 1;
                        const int lup = ((((q & 1) << 1) + (col >> 3)) << 4);
                        const int j = col & 7;
#pragma unroll
                        for (int r = 0; r < 4; ++r) {
                            const int m = quad * 4 + r;
                            const float iv = sigf(acc[qi * 4 + 0][r]);
                            const float fv = sigf(acc[qi * 4 + 1][r]);
                            const float gv = tanh_(acc[qi * 4 + 2][r]);
                            const float ov = sigf(acc[qi * 4 + 3][r]);
                            c3[q][r] = fv * c3[q][r] + iv * gv;
                            const float h = ov * tanh_(c3[q][r]);
                            hout[(kt * 64 + m + lup) * 8 + j] = f2bf(h);
                        }
                    }
                }
            }
        } else {
            if (s >= 1) {
                // ---- back: dec2 for t=s-1 ----
                const int t = s - 1;
                const u16* hprev = h1d + (((s + 1) & 1) << 10);   // h3[t]
                const bf16x8 a3h0 = *reinterpret_cast<const bf16x8*>(hprev + lane * 8);
                const bf16x8 a3h1 = *reinterpret_cast<const bf16x8*>(hprev + (64 + lane) * 8);
                f32x4 acc4 = splat4(bias4r);
                {
                    const float4 w4 = *reinterpret_cast<const float4*>(W4hhF + col * 4);
#pragma unroll
                    for (int r = 0; r < 4; ++r) {
                        const float4 hv = *reinterpret_cast<const float4*>(bufH4 + (quad * 4 + r) * 4);
                        float sa = acc4[r];
                        sa = fmaf(w4.x, hv.x, sa);
                        sa = fmaf(w4.y, hv.y, sa);
                        sa = fmaf(w4.z, hv.z, sa);
                        sa = fmaf(w4.w, hv.w, sa);
                        acc4[r] = sa;
                    }
                }
                {
                    const bf16x8 bh0 = *reinterpret_cast<const bf16x8*>(Wih4hi + (0 * 64 + lane) * 8);
                    const bf16x8 bh1 = *reinterpret_cast<const bf16x8*>(Wih4hi + (1 * 64 + lane) * 8);
                    acc4 = MFMA(a3h0, bh0, acc4);
                    acc4 = MFMA(a3h1, bh1, acc4);
                }
                WB();
#pragma unroll
                for (int r = 0; r < 4; ++r) gbuf[(quad * 4 + r) * 16 + col] = acc4[r];
                WB();
                {   // epilogue: lane = (batch mb, unit u4)
                    const float iv = sigf(gbuf[mb * 16 + u4]);
                    const float fv = sigf(gbuf[mb * 16 + 4 + u4]);
                    const float gv = tanh_(gbuf[mb * 16 + 8 + u4]);
                    const float ov = sigf(gbuf[mb * 16 + 12 + u4]);
                    c4 = fv * c4 + iv * gv;
                    const float h = ov * tanh_(c4);
                    out[((size_t)(b0w + mb) * TT + t) * IN + u4] = h;
                    bufH4[mb * 4 + u4] = h;
                }
                WB();
            }
        }
        __syncthreads();
    }
}

extern "C" void kernel_launch(void* const* d_in, const int* in_sizes, int n_in,
                              void* d_out, int out_size, void* d_ws, size_t ws_size,
                              hipStream_t stream) {
    (void)in_sizes; (void)n_in; (void)d_ws; (void)ws_size; (void)out_size;
    hipFuncSetAttribute(reinterpret_cast<const void*>(lstm_ae),
                        hipFuncAttributeMaxDynamicSharedMemorySize, SMEM_BYTES);
    const float* xi = (const float*)d_in[0];
    const float* w1ih = (const float*)d_in[1];
    const float* w1hh = (const float*)d_in[2];
    const float* b1i = (const float*)d_in[3];
    const float* b1h = (const float*)d_in[4];
    const float* w2ih = (const float*)d_in[5];
    const float* w2hh = (const float*)d_in[6];
    const float* b2i = (const float*)d_in[7];
    const float* b2h = (const float*)d_in[8];
    const float* w3ih = (const float*)d_in[9];
    const float* w3hh = (const float*)d_in[10];
    const float* b3i = (const float*)d_in[11];
    const float* b3h = (const float*)d_in[12];
    const float* w4ih = (const float*)d_in[13];
    const float* w4hh = (const float*)d_in[14];
    const float* b4i = (const float*)d_in[15];
    const float* b4h = (const float*)d_in[16];
    float* out = (float*)d_out;

    lstm_ae<<<dim3(BATCH / BPB), dim3(BLOCKT), SMEM_BYTES, stream>>>(
        xi, w1ih, w1hh, b1i, b1h, w2ih, w2hh, b2i, b2h,
        w3ih, w3hh, b3i, b3h, w4ih, w4hh, b4i, b4h, out);
}

// Round 12
// 338.247 us; speedup vs baseline: 1.2668x; 1.2668x over previous
//
#include <hip/hip_runtime.h>
#include <stdint.h>

// LSTM autoencoder B=32768 T=30 I=4 H=64 L=32, fp32 in/out.
// v12 = v11 (layer-pipelined, 16 waves/block) + register-allocator fix.
// v11 post-mortem: occupancy 45.8% achieved, logic correct, but the backend
// targeted 8 waves/EU (VGPR=64) despite launch_bounds(1024,4) being only a
// MINIMUM -> ~100-reg working set spilled to scratch (FETCH 240MB, WRITE
// 177MB, HBM 1 TB/s). Fix: amdgpu_waves_per_eu(4,4) pins min=max=4 waves/EU
// -> VGPR budget exactly 128, no spill. Also bias3 moved from a 16-reg
// array to per-nt LDS reads (pressure trim).
// Structure: front wave (role 0) enc1/dec1 t=s; back wave (role 1)
// enc2/dec2 t=s-1; h1/h3 via double-buffered LDS A-tile; one
// __syncthreads/step. 1-term bf16 MFMA everywhere (absmax pinned at the
// fp32 floor 9.77e-4 since v4).
// Layouts (HW-verified): C/D col=lane&15,row=(lane>>4)*4+reg [m89];
// A m=lane&15,k=(lane>>4)*8+j [m120]; B n=lane&15,k=(lane>>4)*8+j.

typedef unsigned short u16;
typedef unsigned int u32;
typedef __attribute__((ext_vector_type(8))) short bf16x8;
typedef __attribute__((ext_vector_type(4))) short s16x4;
typedef __attribute__((ext_vector_type(4))) float f32x4;

#define BATCH 32768
#define TT 30
#define IN 4
#define WAVES 16
#define BLOCKT (WAVES * 64)   // 1024
#define MB 16
#define NPAIR 8
#define BPB (NPAIR * MB)      // 128 batches/block -> grid 256, 1 round

// ---- LDS word (u32/float) offsets ----
#define WREG 18432
// enc phase
#define O_WHH1HI 0       // 8192 words (32 frags)
#define O_W1FOLD 8192    // 4096 words (16 frags: x+bias fold tile)
#define O_WIH2HI 12288   // 4096
#define O_WHH2HI 16384   // 2048 -> 18432
// dec phase (same region)
#define O_WHH3HI 0       // 8192
#define O_WIH3HI 8192    // 4096
#define O_WIH4HI 12288   // 512
#define O_W4HHF  12800   // 64 fp32 -> 12864

#define NBIAS 400   // b2[128] @0 | b3[256] @128 | b4[16] @384
// per-pair floats: h1/h3 dbuf 1024 (2 x 512) | h2 256 | xfold/gbuf 256 | h4 64
#define PBUF 1600
#define SMEM_WORDS (WREG + NBIAS + NPAIR * PBUF)   // 31632
#define SMEM_BYTES (SMEM_WORDS * 4)                // 126528 <= 163840

#define WB() __builtin_amdgcn_wave_barrier()
#define MFMA(a, b, c) __builtin_amdgcn_mfma_f32_16x16x32_bf16((a), (b), (c), 0, 0, 0)

__device__ __forceinline__ u16 f2bf(float f) {   // RNE fp32->bf16
    u32 u = __float_as_uint(f);
    u += 0x7fffu + ((u >> 16) & 1u);
    return (u16)(u >> 16);
}
__device__ __forceinline__ float bf2f(u16 v) { return __uint_as_float(((u32)v) << 16); }
__device__ __forceinline__ float sigf(float x) {
    return __builtin_amdgcn_rcpf(1.f + __expf(-x));
}
__device__ __forceinline__ float tanh_(float x) {
    const float t = __expf(2.f * x);
    return fmaf(-2.f, __builtin_amdgcn_rcpf(t + 1.f), 1.f);
}

// Stage fp32 W[N][K] -> bf16 hi, B-fragment order:
// u16 idx = ((nt*KT + kt)*64 + l)*8 + j, n = nt*16+(l&15), k = kt*32+((l>>4)<<3)+j
template <int KT>
__device__ __forceinline__ void stageBh(u16* hi, const float* src, int N, int tid) {
    const int K = KT * 32;
    const int total = N * K;
    for (int idx = tid; idx < total; idx += BLOCKT) {
        const int j = idx & 7;
        const int l = (idx >> 3) & 63;
        const int pair = idx >> 9;
        const int kt = pair & (KT - 1);
        const int nt = pair / KT;
        const int n = (nt << 4) | (l & 15);
        const int k = (kt << 5) + ((l >> 4) << 3) + j;
        hi[idx] = f2bf(src[n * K + k]);
    }
}

__device__ __forceinline__ f32x4 splat4(float b) {
    f32x4 v = {b, b, b, b};
    return v;
}

__global__ __launch_bounds__(BLOCKT)
__attribute__((amdgpu_waves_per_eu(4, 4)))
void lstm_ae(
    const float* __restrict__ x,
    const float* __restrict__ w1ih, const float* __restrict__ w1hh,
    const float* __restrict__ b1i, const float* __restrict__ b1h,
    const float* __restrict__ w2ih, const float* __restrict__ w2hh,
    const float* __restrict__ b2i, const float* __restrict__ b2h,
    const float* __restrict__ w3ih, const float* __restrict__ w3hh,
    const float* __restrict__ b3i, const float* __restrict__ b3h,
    const float* __restrict__ w4ih, const float* __restrict__ w4hh,
    const float* __restrict__ b4i, const float* __restrict__ b4h,
    float* __restrict__ out) {
    extern __shared__ float smem[];
    float* W = smem;
    float* biasF = smem + WREG;        // b2[128] b3[256] b4[16]
    float* bufs = biasF + NBIAS;

    const int tid = threadIdx.x;
    const int wave = tid >> 6, lane = tid & 63;
    const int pair = wave & 7, role = wave >> 3;   // 0=front(enc1/dec1) 1=back(enc2/dec2)
    const int col = lane & 15, quad = lane >> 4;

    float* pb = bufs + pair * PBUF;
    u16* h1d = (u16*)pb;               // 2048 u16: dbuf parity p at p*1024
    u16* h2b = (u16*)(pb + 1024);      // 512 u16 (h2/latent, 1 k-tile)
    u16* xfold = (u16*)(pb + 1280);    // 512 u16 (front, enc) / gbuf (back, dec)
    float* gbuf = pb + 1280;           // [16 batch][16 gate] fp32 (back, dec)
    float* bufH4 = pb + 1536;          // [16 batch][4] fp32 (back, dec)

    const int b0w = blockIdx.x * BPB + pair * MB;

    // ---------------- stage ENCODER weights + biases ----------------
    stageBh<2>((u16*)(W + O_WHH1HI), w1hh, 256, tid);
    stageBh<2>((u16*)(W + O_WIH2HI), w2ih, 128, tid);
    stageBh<1>((u16*)(W + O_WHH2HI), w2hh, 128, tid);
    // fold tile: B kt per nt: k0-3 whi | k4-7 whi | k8-11 wlo | k12 bias_hi | k13 bias_lo
    {
        u16* F = (u16*)(W + O_W1FOLD);
        for (int idx = tid; idx < 16 * 512; idx += BLOCKT) {
            const int nt = idx >> 9;
            const int rem = idx & 511;
            const int l = rem >> 3;
            const int j = rem & 7;
            const int q = l >> 4;
            const int n = (nt << 4) | (l & 15);
            u16 v = 0;
            if (q == 0) {
                v = f2bf(w1ih[n * 4 + (j & 3)]);
            } else if (q == 1) {
                if (j < 4) {
                    const float w = w1ih[n * 4 + j];
                    v = f2bf(w - bf2f(f2bf(w)));
                } else if (j == 4) {
                    v = f2bf(b1i[n] + b1h[n]);
                } else if (j == 5) {
                    const float b = b1i[n] + b1h[n];
                    v = f2bf(b - bf2f(f2bf(b)));
                }
            }
            F[idx] = v;
        }
    }
    for (int i = tid; i < 128; i += BLOCKT) biasF[i] = b2i[i] + b2h[i];
    for (int i = tid; i < 256; i += BLOCKT) biasF[128 + i] = b3i[i] + b3h[i];
    for (int i = tid; i < 16; i += BLOCKT) biasF[384 + i] = b4i[i] + b4h[i];
    // zero pair buffers (front: dbuf+xfold, back: h2+h4), set xfold 1.0 slots
    {
        u32* z = (u32*)pb;
        if (role == 0) {
            for (int i = lane; i < 1024; i += 64) z[i] = 0u;
            for (int i = lane; i < 256; i += 64) z[1280 + i] = 0u;
        } else {
            for (int i = lane; i < 256; i += 64) z[1024 + i] = 0u;
            if (lane < 64) bufH4[lane] = 0.f;
        }
    }
    WB();
    if (role == 0 && quad == 1) {
        xfold[lane * 8 + 4] = (u16)0x3F80;   // bf16(1.0) pairs bias_hi
        xfold[lane * 8 + 5] = (u16)0x3F80;   // bf16(1.0) pairs bias_lo
    }
    __syncthreads();

    const u16* Whh1hi = (const u16*)(W + O_WHH1HI);
    const u16* W1fold = (const u16*)(W + O_W1FOLD);
    const u16* Wih2hi = (const u16*)(W + O_WIH2HI);
    const u16* Whh2hi = (const u16*)(W + O_WHH2HI);

    // ================= encoder (pipelined) =================
    float c1[4][4];   // front: [q][r]
    float c2[2][4];   // back
#pragma unroll
    for (int q = 0; q < 4; ++q)
#pragma unroll
        for (int r = 0; r < 4; ++r) c1[q][r] = 0.f;
#pragma unroll
    for (int q = 0; q < 2; ++q)
#pragma unroll
        for (int r = 0; r < 4; ++r) c2[q][r] = 0.f;

    const f32x4 zf = {0.f, 0.f, 0.f, 0.f};
    float4 xcur;
    if (role == 0)
        xcur = *reinterpret_cast<const float4*>(x + ((size_t)(b0w + col) * TT + 0) * IN);

    for (int s = 0; s <= TT; ++s) {
        if (role == 0) {
            if (s < TT) {
                // ---- front: enc1 for t=s ----
                {   // write x into the fold A-tile
                    const u16 xh0 = f2bf(xcur.x), xh1 = f2bf(xcur.y);
                    const u16 xh2 = f2bf(xcur.z), xh3 = f2bf(xcur.w);
                    if (quad == 0) {
                        bf16x8 v;
                        v[0] = (short)xh0; v[1] = (short)xh1; v[2] = (short)xh2; v[3] = (short)xh3;
                        v[4] = (short)f2bf(xcur.x - bf2f(xh0));
                        v[5] = (short)f2bf(xcur.y - bf2f(xh1));
                        v[6] = (short)f2bf(xcur.z - bf2f(xh2));
                        v[7] = (short)f2bf(xcur.w - bf2f(xh3));
                        *reinterpret_cast<bf16x8*>(xfold + lane * 8) = v;
                    } else if (quad == 1) {
                        s16x4 v;
                        v[0] = (short)xh0; v[1] = (short)xh1; v[2] = (short)xh2; v[3] = (short)xh3;
                        *reinterpret_cast<s16x4*>(xfold + lane * 8) = v;
                    }
                }
                WB();
                {   // prefetch next x
                    const int tn = (s + 1 < TT) ? s + 1 : s;
                    xcur = *reinterpret_cast<const float4*>(
                        x + ((size_t)(b0w + col) * TT + tn) * IN);
                }
                const u16* hprev = h1d + (((s + 1) & 1) << 10);   // h1[s-1]
                u16* hout = h1d + ((s & 1) << 10);                // h1[s]
                const bf16x8 a1h0 = *reinterpret_cast<const bf16x8*>(hprev + lane * 8);
                const bf16x8 a1h1 = *reinterpret_cast<const bf16x8*>(hprev + (64 + lane) * 8);
                const bf16x8 a1x = *reinterpret_cast<const bf16x8*>(xfold + lane * 8);
#pragma unroll
                for (int half = 0; half < 2; ++half) {
                    f32x4 acc[8];
#pragma unroll
                    for (int i = 0; i < 8; ++i) {
                        const int q = half * 2 + (i >> 2);
                        const int nt = (i & 3) * 4 + q;
                        const bf16x8 bx = *reinterpret_cast<const bf16x8*>(W1fold + (nt * 64 + lane) * 8);
                        const bf16x8 bh0 = *reinterpret_cast<const bf16x8*>(Whh1hi + ((nt * 2 + 0) * 64 + lane) * 8);
                        const bf16x8 bh1 = *reinterpret_cast<const bf16x8*>(Whh1hi + ((nt * 2 + 1) * 64 + lane) * 8);
                        f32x4 a = MFMA(a1x, bx, zf);
                        a = MFMA(a1h0, bh0, a);
                        a = MFMA(a1h1, bh1, a);
                        acc[i] = a;
                    }
#pragma unroll
                    for (int qi = 0; qi < 2; ++qi) {
                        const int q = half * 2 + qi;
                        const int kt = q >> 1;
                        const int lup = ((((q & 1) << 1) + (col >> 3)) << 4);
                        const int j = col & 7;
#pragma unroll
                        for (int r = 0; r < 4; ++r) {
                            const int m = quad * 4 + r;
                            const float iv = sigf(acc[qi * 4 + 0][r]);
                            const float fv = sigf(acc[qi * 4 + 1][r]);
                            const float gv = tanh_(acc[qi * 4 + 2][r]);
                            const float ov = sigf(acc[qi * 4 + 3][r]);
                            c1[q][r] = fv * c1[q][r] + iv * gv;
                            const float h = ov * tanh_(c1[q][r]);
                            hout[(kt * 64 + m + lup) * 8 + j] = f2bf(h);
                        }
                    }
                }
            }
        } else {
            if (s >= 1) {
                // ---- back: enc2 for t=s-1 ----
                const u16* hprev = h1d + (((s + 1) & 1) << 10);   // h1[s-1]
                const bf16x8 a1h0 = *reinterpret_cast<const bf16x8*>(hprev + lane * 8);
                const bf16x8 a1h1 = *reinterpret_cast<const bf16x8*>(hprev + (64 + lane) * 8);
                const bf16x8 a2h = *reinterpret_cast<const bf16x8*>(h2b + lane * 8);
                f32x4 acc2[8];
#pragma unroll
                for (int nt = 0; nt < 8; ++nt) {
                    const bf16x8 bh0 = *reinterpret_cast<const bf16x8*>(Wih2hi + ((nt * 2 + 0) * 64 + lane) * 8);
                    const bf16x8 bh1 = *reinterpret_cast<const bf16x8*>(Wih2hi + ((nt * 2 + 1) * 64 + lane) * 8);
                    const bf16x8 ch = *reinterpret_cast<const bf16x8*>(Whh2hi + (nt * 64 + lane) * 8);
                    f32x4 a = splat4(biasF[nt * 16 + col]);
                    a = MFMA(a1h0, bh0, a);
                    a = MFMA(a1h1, bh1, a);
                    a = MFMA(a2h, ch, a);
                    acc2[nt] = a;
                }
                WB();   // a2h read before h2 overwrite
#pragma unroll
                for (int q = 0; q < 2; ++q) {
                    const int lup = (((q << 1) + (col >> 3)) << 4);
                    const int j = col & 7;
#pragma unroll
                    for (int r = 0; r < 4; ++r) {
                        const int m = quad * 4 + r;
                        const float iv = sigf(acc2[q][r]);
                        const float fv = sigf(acc2[2 + q][r]);
                        const float gv = tanh_(acc2[4 + q][r]);
                        const float ov = sigf(acc2[6 + q][r]);
                        c2[q][r] = fv * c2[q][r] + iv * gv;
                        const float h = ov * tanh_(c2[q][r]);
                        h2b[(m + lup) * 8 + j] = f2bf(h);
                    }
                }
            }
        }
        __syncthreads();
    }
    // h2b holds the latent.

    // ---------------- re-stage DECODER weights ----------------
    stageBh<2>((u16*)(W + O_WHH3HI), w3hh, 256, tid);
    stageBh<1>((u16*)(W + O_WIH3HI), w3ih, 256, tid);
    stageBh<2>((u16*)(W + O_WIH4HI), w4ih, 16, tid);
    for (int i = tid; i < 64; i += BLOCKT) W[O_W4HHF + i] = w4hh[i];
    // zero h3 dbuf (front) + h4 (back)
    if (role == 0) {
        u32* z = (u32*)pb;
        for (int i = lane; i < 1024; i += 64) z[i] = 0u;
    } else {
        if (lane < 64) bufH4[lane] = 0.f;
    }
    __syncthreads();

    const u16* Whh3hi = (const u16*)(W + O_WHH3HI);
    const u16* Wih3hi = (const u16*)(W + O_WIH3HI);
    const u16* Wih4hi = (const u16*)(W + O_WIH4HI);
    const float* W4hhF = W + O_W4HHF;

    // ================= decoder (pipelined) =================
    float c3[4][4];
    float c4 = 0.f, bias4r = 0.f;
    bf16x8 aLh;
    if (role == 0) {
#pragma unroll
        for (int q = 0; q < 4; ++q)
#pragma unroll
            for (int r = 0; r < 4; ++r) c3[q][r] = 0.f;
        aLh = *reinterpret_cast<const bf16x8*>(h2b + lane * 8);   // latent A-frag
    } else {
        bias4r = biasF[384 + col];
    }
    const int u4 = lane & 3, mb = lane >> 2;   // back dec2 epilogue task

    for (int s = 0; s <= TT; ++s) {
        if (role == 0) {
            if (s < TT) {
                // ---- front: dec1 for t=s ----
                const u16* hprev = h1d + (((s + 1) & 1) << 10);   // h3[s-1]
                u16* hout = h1d + ((s & 1) << 10);                // h3[s]
                const bf16x8 a3h0 = *reinterpret_cast<const bf16x8*>(hprev + lane * 8);
                const bf16x8 a3h1 = *reinterpret_cast<const bf16x8*>(hprev + (64 + lane) * 8);
#pragma unroll
                for (int half = 0; half < 2; ++half) {
                    f32x4 acc[8];
#pragma unroll
                    for (int i = 0; i < 8; ++i) {
                        const int q = half * 2 + (i >> 2);
                        const int nt = (i & 3) * 4 + q;
                        const bf16x8 bL = *reinterpret_cast<const bf16x8*>(Wih3hi + (nt * 64 + lane) * 8);
                        const bf16x8 bh0 = *reinterpret_cast<const bf16x8*>(Whh3hi + ((nt * 2 + 0) * 64 + lane) * 8);
                        const bf16x8 bh1 = *reinterpret_cast<const bf16x8*>(Whh3hi + ((nt * 2 + 1) * 64 + lane) * 8);
                        f32x4 a = MFMA(aLh, bL, splat4(biasF[128 + nt * 16 + col]));
                        a = MFMA(a3h0, bh0, a);
                        a = MFMA(a3h1, bh1, a);
                        acc[i] = a;
                    }
#pragma unroll
                    for (int qi = 0; qi < 2; ++qi) {
                        const int q = half * 2 + qi;
                        const int kt = q >> 1;
                        const int lup = ((((q & 1) << 1) + (col >> 3)) << 4);
                        const int j = col & 7;
#pragma unroll
                        for (int r = 0; r < 4; ++r) {
                            const int m = quad * 4 + r;
                            const float iv = sigf(acc[qi * 4 + 0][r]);
                            const float fv = sigf(acc[qi * 4 + 1][r]);
                            const float gv = tanh_(acc[qi * 4 + 2][r]);
                            const float ov = sigf(acc[qi * 4 + 3][r]);
                            c3[q][r] = fv * c3[q][r] + iv * gv;
                            const float h = ov * tanh_(c3[q][r]);
                            hout[(kt * 64 + m + lup) * 8 + j] = f2bf(h);
                        }
                    }
                }
            }
        } else {
            if (s >= 1) {
                // ---- back: dec2 for t=s-1 ----
                const int t = s - 1;
                const u16* hprev = h1d + (((s + 1) & 1) << 10);   // h3[t]
                const bf16x8 a3h0 = *reinterpret_cast<const bf16x8*>(hprev + lane * 8);
                const bf16x8 a3h1 = *reinterpret_cast<const bf16x8*>(hprev + (64 + lane) * 8);
                f32x4 acc4 = splat4(bias4r);
                {
                    const float4 w4 = *reinterpret_cast<const float4*>(W4hhF + col * 4);
#pragma unroll
                    for (int r = 0; r < 4; ++r) {
                        const float4 hv = *reinterpret_cast<const float4*>(bufH4 + (quad * 4 + r) * 4);
                        float sa = acc4[r];
                        sa = fmaf(w4.x, hv.x, sa);
                        sa = fmaf(w4.y, hv.y, sa);
                        sa = fmaf(w4.z, hv.z, sa);
                        sa = fmaf(w4.w, hv.w, sa);
                        acc4[r] = sa;
                    }
                }
                {
                    const bf16x8 bh0 = *reinterpret_cast<const bf16x8*>(Wih4hi + (0 * 64 + lane) * 8);
                    const bf16x8 bh1 = *reinterpret_cast<const bf16x8*>(Wih4hi + (1 * 64 + lane) * 8);
                    acc4 = MFMA(a3h0, bh0, acc4);
                    acc4 = MFMA(a3h1, bh1, acc4);
                }
                WB();
#pragma unroll
                for (int r = 0; r < 4; ++r) gbuf[(quad * 4 + r) * 16 + col] = acc4[r];
                WB();
                {   // epilogue: lane = (batch mb, unit u4)
                    const float iv = sigf(gbuf[mb * 16 + u4]);
                    const float fv = sigf(gbuf[mb * 16 + 4 + u4]);
                    const float gv = tanh_(gbuf[mb * 16 + 8 + u4]);
                    const float ov = sigf(gbuf[mb * 16 + 12 + u4]);
                    c4 = fv * c4 + iv * gv;
                    const float h = ov * tanh_(c4);
                    out[((size_t)(b0w + mb) * TT + t) * IN + u4] = h;
                    bufH4[mb * 4 + u4] = h;
                }
                WB();
            }
        }
        __syncthreads();
    }
}

extern "C" void kernel_launch(void* const* d_in, const int* in_sizes, int n_in,
                              void* d_out, int out_size, void* d_ws, size_t ws_size,
                              hipStream_t stream) {
    (void)in_sizes; (void)n_in; (void)d_ws; (void)ws_size; (void)out_size;
    hipFuncSetAttribute(reinterpret_cast<const void*>(lstm_ae),
                        hipFuncAttributeMaxDynamicSharedMemorySize, SMEM_BYTES);
    const float* xi = (const float*)d_in[0];
    const float* w1ih = (const float*)d_in[1];
    const float* w1hh = (const float*)d_in[2];
    const float* b1i = (const float*)d_in[3];
    const float* b1h = (const float*)d_in[4];
    const float* w2ih = (const float*)d_in[5];
    const float* w2hh = (const float*)d_in[6];
    const float* b2i = (const float*)d_in[7];
    const float* b2h = (const float*)d_in[8];
    const float* w3ih = (const float*)d_in[9];
    const float* w3hh = (const float*)d_in[10];
    const float* b3i = (const float*)d_in[11];
    const float* b3h = (const float*)d_in[12];
    const float* w4ih = (const float*)d_in[13];
    const float* w4hh = (const float*)d_in[14];
    const float* b4i = (const float*)d_in[15];
    const float* b4h = (const float*)d_in[16];
    float* out = (float*)d_out;

    lstm_ae<<<dim3(BATCH / BPB), dim3(BLOCKT), SMEM_BYTES, stream>>>(
        xi, w1ih, w1hh, b1i, b1h, w2ih, w2hh, b2i, b2h,
        w3ih, w3hh, b3i, b3h, w4ih, w4hh, b4i, b4h, out);
}

// Round 13
// 311.153 us; speedup vs baseline: 1.3771x; 1.0871x over previous
//
#include <hip/hip_runtime.h>
#include <stdint.h>

// LSTM autoencoder B=32768 T=30 I=4 H=64 L=32, fp32 in/out.
// v13 = v12 (338us) + two VALU cuts:
//  1. Front-wave MFMA loop quartered (acc[4], nt=i*4+q = the 4 gates of
//     unit-group q) -> peak live regs ~50, fits VGPR=64 with ZERO spill
//     (v12 still wrote ~10MB of scratch).
//  2. log2e folded into weights at staging: gate rows i,f,o scaled by
//     log2(e), g rows by 2*log2(e) -> activations use raw v_exp_f32 (exp2)
//     with no per-call multiply: sig(y)=rcp(1+exp2(-y)),
//     tanh(y)=1-2*rcp(exp2(y)+1). Only tanh(c) keeps one mul.
// Structure: layer-pipelined, 16 waves/block (1024 thr), 8 pairs x 16
// batches, grid 256, 4 waves/SIMD. 1-term bf16 MFMA (absmax pinned at the
// fp32 floor 9.77e-4 since v4).
// Layouts (HW-verified): C/D col=lane&15,row=(lane>>4)*4+reg [m89];
// A m=lane&15,k=(lane>>4)*8+j [m120]; B n=lane&15,k=(lane>>4)*8+j.

typedef unsigned short u16;
typedef unsigned int u32;
typedef __attribute__((ext_vector_type(8))) short bf16x8;
typedef __attribute__((ext_vector_type(4))) short s16x4;
typedef __attribute__((ext_vector_type(4))) float f32x4;

#define BATCH 32768
#define TT 30
#define IN 4
#define WAVES 16
#define BLOCKT (WAVES * 64)   // 1024
#define MB 16
#define NPAIR 8
#define BPB (NPAIR * MB)      // 128 batches/block -> grid 256, 1 round

#define LOG2E 1.4426950408889634f
#define LOG2E2 2.8853900817779268f

// ---- LDS word (u32/float) offsets ----
#define WREG 18432
// enc phase
#define O_WHH1HI 0       // 8192 words (32 frags)
#define O_W1FOLD 8192    // 4096 words (16 frags: x+bias fold tile)
#define O_WIH2HI 12288   // 4096
#define O_WHH2HI 16384   // 2048 -> 18432
// dec phase (same region)
#define O_WHH3HI 0       // 8192
#define O_WIH3HI 8192    // 4096
#define O_WIH4HI 12288   // 512
#define O_W4HHF  12800   // 64 fp32 -> 12864

#define NBIAS 400   // b2[128] @0 | b3[256] @128 | b4[16] @384
// per-pair floats: h1/h3 dbuf 1024 (2 x 512) | h2 256 | xfold/gbuf 256 | h4 64
#define PBUF 1600
#define SMEM_WORDS (WREG + NBIAS + NPAIR * PBUF)   // 31632
#define SMEM_BYTES (SMEM_WORDS * 4)                // 126528 <= 163840

#define WB() __builtin_amdgcn_wave_barrier()
#define MFMA(a, b, c) __builtin_amdgcn_mfma_f32_16x16x32_bf16((a), (b), (c), 0, 0, 0)

__device__ __forceinline__ u16 f2bf(float f) {   // RNE fp32->bf16
    u32 u = __float_as_uint(f);
    u += 0x7fffu + ((u >> 16) & 1u);
    return (u16)(u >> 16);
}
__device__ __forceinline__ float bf2f(u16 v) { return __uint_as_float(((u32)v) << 16); }
// y is pre-scaled by log2e (sig) / 2*log2e (tanh) via the weights.
__device__ __forceinline__ float sigY(float y) {
    return __builtin_amdgcn_rcpf(1.f + __builtin_amdgcn_exp2f(-y));
}
__device__ __forceinline__ float tanhY(float y) {
    return fmaf(-2.f, __builtin_amdgcn_rcpf(__builtin_amdgcn_exp2f(y) + 1.f), 1.f);
}
__device__ __forceinline__ float tanhC(float c) { return tanhY(c * LOG2E2); }

// Stage fp32 W[N][K] -> bf16 hi, B-fragment order, rows pre-scaled by
// gate factor (gate = (n>>GS)&3; g-gate (==2) gets 2*log2e, else log2e).
// u16 idx = ((nt*KT + kt)*64 + l)*8 + j, n = nt*16+(l&15), k = kt*32+((l>>4)<<3)+j
template <int KT, int GS>
__device__ __forceinline__ void stageBh(u16* hi, const float* src, int N, int tid) {
    const int K = KT * 32;
    const int total = N * K;
    for (int idx = tid; idx < total; idx += BLOCKT) {
        const int j = idx & 7;
        const int l = (idx >> 3) & 63;
        const int pr = idx >> 9;
        const int kt = pr & (KT - 1);
        const int nt = pr / KT;
        const int n = (nt << 4) | (l & 15);
        const int k = (kt << 5) + ((l >> 4) << 3) + j;
        const float s = (((n >> GS) & 3) == 2) ? LOG2E2 : LOG2E;
        hi[idx] = f2bf(src[n * K + k] * s);
    }
}

__device__ __forceinline__ f32x4 splat4(float b) {
    f32x4 v = {b, b, b, b};
    return v;
}

__global__ __launch_bounds__(BLOCKT)
__attribute__((amdgpu_waves_per_eu(4, 4)))
void lstm_ae(
    const float* __restrict__ x,
    const float* __restrict__ w1ih, const float* __restrict__ w1hh,
    const float* __restrict__ b1i, const float* __restrict__ b1h,
    const float* __restrict__ w2ih, const float* __restrict__ w2hh,
    const float* __restrict__ b2i, const float* __restrict__ b2h,
    const float* __restrict__ w3ih, const float* __restrict__ w3hh,
    const float* __restrict__ b3i, const float* __restrict__ b3h,
    const float* __restrict__ w4ih, const float* __restrict__ w4hh,
    const float* __restrict__ b4i, const float* __restrict__ b4h,
    float* __restrict__ out) {
    extern __shared__ float smem[];
    float* W = smem;
    float* biasF = smem + WREG;        // b2[128] b3[256] b4[16] (pre-scaled)
    float* bufs = biasF + NBIAS;

    const int tid = threadIdx.x;
    const int wave = tid >> 6, lane = tid & 63;
    const int pair = wave & 7, role = wave >> 3;   // 0=front(enc1/dec1) 1=back(enc2/dec2)
    const int col = lane & 15, quad = lane >> 4;

    float* pb = bufs + pair * PBUF;
    u16* h1d = (u16*)pb;               // 2048 u16: dbuf parity p at p*1024
    u16* h2b = (u16*)(pb + 1024);      // 512 u16 (h2/latent, 1 k-tile)
    u16* xfold = (u16*)(pb + 1280);    // 512 u16 (front, enc) / gbuf (back, dec)
    float* gbuf = pb + 1280;           // [16 batch][16 gate] fp32 (back, dec)
    float* bufH4 = pb + 1536;          // [16 batch][4] fp32 (back, dec)

    const int b0w = blockIdx.x * BPB + pair * MB;

    // ---------------- stage ENCODER weights + biases (pre-scaled) ----------------
    stageBh<2, 6>((u16*)(W + O_WHH1HI), w1hh, 256, tid);
    stageBh<2, 5>((u16*)(W + O_WIH2HI), w2ih, 128, tid);
    stageBh<1, 5>((u16*)(W + O_WHH2HI), w2hh, 128, tid);
    // fold tile: B kt per nt: k0-3 whi | k4-7 whi | k8-11 wlo | k12 bias_hi | k13 bias_lo
    {
        u16* F = (u16*)(W + O_W1FOLD);
        for (int idx = tid; idx < 16 * 512; idx += BLOCKT) {
            const int nt = idx >> 9;
            const int rem = idx & 511;
            const int l = rem >> 3;
            const int j = rem & 7;
            const int q = l >> 4;
            const int n = (nt << 4) | (l & 15);
            const float s = ((n >> 6) == 2) ? LOG2E2 : LOG2E;
            u16 v = 0;
            if (q == 0) {
                v = f2bf(w1ih[n * 4 + (j & 3)] * s);
            } else if (q == 1) {
                if (j < 4) {
                    const float w = w1ih[n * 4 + j] * s;
                    v = f2bf(w - bf2f(f2bf(w)));
                } else if (j == 4) {
                    v = f2bf((b1i[n] + b1h[n]) * s);
                } else if (j == 5) {
                    const float b = (b1i[n] + b1h[n]) * s;
                    v = f2bf(b - bf2f(f2bf(b)));
                }
            }
            F[idx] = v;
        }
    }
    for (int i = tid; i < 128; i += BLOCKT)
        biasF[i] = (b2i[i] + b2h[i]) * ((((i >> 5) & 3) == 2) ? LOG2E2 : LOG2E);
    for (int i = tid; i < 256; i += BLOCKT)
        biasF[128 + i] = (b3i[i] + b3h[i]) * ((((i >> 6) & 3) == 2) ? LOG2E2 : LOG2E);
    for (int i = tid; i < 16; i += BLOCKT)
        biasF[384 + i] = (b4i[i] + b4h[i]) * ((((i >> 2) & 3) == 2) ? LOG2E2 : LOG2E);
    // zero pair buffers, set xfold 1.0 slots
    {
        u32* z = (u32*)pb;
        if (role == 0) {
            for (int i = lane; i < 1024; i += 64) z[i] = 0u;
            for (int i = lane; i < 256; i += 64) z[1280 + i] = 0u;
        } else {
            for (int i = lane; i < 256; i += 64) z[1024 + i] = 0u;
            if (lane < 64) bufH4[lane] = 0.f;
        }
    }
    WB();
    if (role == 0 && quad == 1) {
        xfold[lane * 8 + 4] = (u16)0x3F80;   // bf16(1.0) pairs bias_hi
        xfold[lane * 8 + 5] = (u16)0x3F80;   // bf16(1.0) pairs bias_lo
    }
    __syncthreads();

    const u16* Whh1hi = (const u16*)(W + O_WHH1HI);
    const u16* W1fold = (const u16*)(W + O_W1FOLD);
    const u16* Wih2hi = (const u16*)(W + O_WIH2HI);
    const u16* Whh2hi = (const u16*)(W + O_WHH2HI);

    // ================= encoder (pipelined) =================
    float c1[4][4];   // front: [q][r]
    float c2[2][4];   // back
#pragma unroll
    for (int q = 0; q < 4; ++q)
#pragma unroll
        for (int r = 0; r < 4; ++r) c1[q][r] = 0.f;
#pragma unroll
    for (int q = 0; q < 2; ++q)
#pragma unroll
        for (int r = 0; r < 4; ++r) c2[q][r] = 0.f;

    const f32x4 zf = {0.f, 0.f, 0.f, 0.f};
    float4 xcur;
    if (role == 0)
        xcur = *reinterpret_cast<const float4*>(x + ((size_t)(b0w + col) * TT + 0) * IN);

    for (int s = 0; s <= TT; ++s) {
        if (role == 0) {
            if (s < TT) {
                // ---- front: enc1 for t=s ----
                {   // write x into the fold A-tile
                    const u16 xh0 = f2bf(xcur.x), xh1 = f2bf(xcur.y);
                    const u16 xh2 = f2bf(xcur.z), xh3 = f2bf(xcur.w);
                    if (quad == 0) {
                        bf16x8 v;
                        v[0] = (short)xh0; v[1] = (short)xh1; v[2] = (short)xh2; v[3] = (short)xh3;
                        v[4] = (short)f2bf(xcur.x - bf2f(xh0));
                        v[5] = (short)f2bf(xcur.y - bf2f(xh1));
                        v[6] = (short)f2bf(xcur.z - bf2f(xh2));
                        v[7] = (short)f2bf(xcur.w - bf2f(xh3));
                        *reinterpret_cast<bf16x8*>(xfold + lane * 8) = v;
                    } else if (quad == 1) {
                        s16x4 v;
                        v[0] = (short)xh0; v[1] = (short)xh1; v[2] = (short)xh2; v[3] = (short)xh3;
                        *reinterpret_cast<s16x4*>(xfold + lane * 8) = v;
                    }
                }
                WB();
                {   // prefetch next x
                    const int tn = (s + 1 < TT) ? s + 1 : s;
                    xcur = *reinterpret_cast<const float4*>(
                        x + ((size_t)(b0w + col) * TT + tn) * IN);
                }
                const u16* hprev = h1d + (((s + 1) & 1) << 10);   // h1[s-1]
                u16* hout = h1d + ((s & 1) << 10);                // h1[s]
                const bf16x8 a1h0 = *reinterpret_cast<const bf16x8*>(hprev + lane * 8);
                const bf16x8 a1h1 = *reinterpret_cast<const bf16x8*>(hprev + (64 + lane) * 8);
                const bf16x8 a1x = *reinterpret_cast<const bf16x8*>(xfold + lane * 8);
#pragma unroll
                for (int q = 0; q < 4; ++q) {   // quarter-loop: acc[4], zero spill
                    f32x4 acc[4];
#pragma unroll
                    for (int i = 0; i < 4; ++i) {
                        const int nt = i * 4 + q;
                        const bf16x8 bx = *reinterpret_cast<const bf16x8*>(W1fold + (nt * 64 + lane) * 8);
                        const bf16x8 bh0 = *reinterpret_cast<const bf16x8*>(Whh1hi + ((nt * 2 + 0) * 64 + lane) * 8);
                        const bf16x8 bh1 = *reinterpret_cast<const bf16x8*>(Whh1hi + ((nt * 2 + 1) * 64 + lane) * 8);
                        f32x4 a = MFMA(a1x, bx, zf);
                        a = MFMA(a1h0, bh0, a);
                        a = MFMA(a1h1, bh1, a);
                        acc[i] = a;
                    }
                    const int kt = q >> 1;
                    const int lup = ((((q & 1) << 1) + (col >> 3)) << 4);
                    const int j = col & 7;
#pragma unroll
                    for (int r = 0; r < 4; ++r) {
                        const int m = quad * 4 + r;
                        const float iv = sigY(acc[0][r]);
                        const float fv = sigY(acc[1][r]);
                        const float gv = tanhY(acc[2][r]);
                        const float ov = sigY(acc[3][r]);
                        c1[q][r] = fv * c1[q][r] + iv * gv;
                        const float h = ov * tanhC(c1[q][r]);
                        hout[(kt * 64 + m + lup) * 8 + j] = f2bf(h);
                    }
                }
            }
        } else {
            if (s >= 1) {
                // ---- back: enc2 for t=s-1 ----
                const u16* hprev = h1d + (((s + 1) & 1) << 10);   // h1[s-1]
                const bf16x8 a1h0 = *reinterpret_cast<const bf16x8*>(hprev + lane * 8);
                const bf16x8 a1h1 = *reinterpret_cast<const bf16x8*>(hprev + (64 + lane) * 8);
                const bf16x8 a2h = *reinterpret_cast<const bf16x8*>(h2b + lane * 8);
                f32x4 acc2[8];
#pragma unroll
                for (int nt = 0; nt < 8; ++nt) {
                    const bf16x8 bh0 = *reinterpret_cast<const bf16x8*>(Wih2hi + ((nt * 2 + 0) * 64 + lane) * 8);
                    const bf16x8 bh1 = *reinterpret_cast<const bf16x8*>(Wih2hi + ((nt * 2 + 1) * 64 + lane) * 8);
                    const bf16x8 ch = *reinterpret_cast<const bf16x8*>(Whh2hi + (nt * 64 + lane) * 8);
                    f32x4 a = splat4(biasF[nt * 16 + col]);
                    a = MFMA(a1h0, bh0, a);
                    a = MFMA(a1h1, bh1, a);
                    a = MFMA(a2h, ch, a);
                    acc2[nt] = a;
                }
                WB();   // a2h read before h2 overwrite
#pragma unroll
                for (int q = 0; q < 2; ++q) {
                    const int lup = (((q << 1) + (col >> 3)) << 4);
                    const int j = col & 7;
#pragma unroll
                    for (int r = 0; r < 4; ++r) {
                        const int m = quad * 4 + r;
                        const float iv = sigY(acc2[q][r]);
                        const float fv = sigY(acc2[2 + q][r]);
                        const float gv = tanhY(acc2[4 + q][r]);
                        const float ov = sigY(acc2[6 + q][r]);
                        c2[q][r] = fv * c2[q][r] + iv * gv;
                        const float h = ov * tanhC(c2[q][r]);
                        h2b[(m + lup) * 8 + j] = f2bf(h);
                    }
                }
            }
        }
        __syncthreads();
    }
    // h2b holds the latent.

    // ---------------- re-stage DECODER weights (pre-scaled) ----------------
    stageBh<2, 6>((u16*)(W + O_WHH3HI), w3hh, 256, tid);
    stageBh<1, 6>((u16*)(W + O_WIH3HI), w3ih, 256, tid);
    stageBh<2, 2>((u16*)(W + O_WIH4HI), w4ih, 16, tid);
    for (int i = tid; i < 64; i += BLOCKT)
        W[O_W4HHF + i] = w4hh[i] * ((((i >> 4) & 3) == 2) ? LOG2E2 : LOG2E);
    // zero h3 dbuf (front) + h4 (back)
    if (role == 0) {
        u32* z = (u32*)pb;
        for (int i = lane; i < 1024; i += 64) z[i] = 0u;
    } else {
        if (lane < 64) bufH4[lane] = 0.f;
    }
    __syncthreads();

    const u16* Whh3hi = (const u16*)(W + O_WHH3HI);
    const u16* Wih3hi = (const u16*)(W + O_WIH3HI);
    const u16* Wih4hi = (const u16*)(W + O_WIH4HI);
    const float* W4hhF = W + O_W4HHF;

    // ================= decoder (pipelined) =================
    float c3[4][4];
    float c4 = 0.f, bias4r = 0.f;
    bf16x8 aLh;
    if (role == 0) {
#pragma unroll
        for (int q = 0; q < 4; ++q)
#pragma unroll
            for (int r = 0; r < 4; ++r) c3[q][r] = 0.f;
        aLh = *reinterpret_cast<const bf16x8*>(h2b + lane * 8);   // latent A-frag
    } else {
        bias4r = biasF[384 + col];
    }
    const int u4 = lane & 3, mb = lane >> 2;   // back dec2 epilogue task

    for (int s = 0; s <= TT; ++s) {
        if (role == 0) {
            if (s < TT) {
                // ---- front: dec1 for t=s ----
                const u16* hprev = h1d + (((s + 1) & 1) << 10);   // h3[s-1]
                u16* hout = h1d + ((s & 1) << 10);                // h3[s]
                const bf16x8 a3h0 = *reinterpret_cast<const bf16x8*>(hprev + lane * 8);
                const bf16x8 a3h1 = *reinterpret_cast<const bf16x8*>(hprev + (64 + lane) * 8);
#pragma unroll
                for (int q = 0; q < 4; ++q) {   // quarter-loop
                    f32x4 acc[4];
#pragma unroll
                    for (int i = 0; i < 4; ++i) {
                        const int nt = i * 4 + q;
                        const bf16x8 bL = *reinterpret_cast<const bf16x8*>(Wih3hi + (nt * 64 + lane) * 8);
                        const bf16x8 bh0 = *reinterpret_cast<const bf16x8*>(Whh3hi + ((nt * 2 + 0) * 64 + lane) * 8);
                        const bf16x8 bh1 = *reinterpret_cast<const bf16x8*>(Whh3hi + ((nt * 2 + 1) * 64 + lane) * 8);
                        f32x4 a = MFMA(aLh, bL, splat4(biasF[128 + nt * 16 + col]));
                        a = MFMA(a3h0, bh0, a);
                        a = MFMA(a3h1, bh1, a);
                        acc[i] = a;
                    }
                    const int kt = q >> 1;
                    const int lup = ((((q & 1) << 1) + (col >> 3)) << 4);
                    const int j = col & 7;
#pragma unroll
                    for (int r = 0; r < 4; ++r) {
                        const int m = quad * 4 + r;
                        const float iv = sigY(acc[0][r]);
                        const float fv = sigY(acc[1][r]);
                        const float gv = tanhY(acc[2][r]);
                        const float ov = sigY(acc[3][r]);
                        c3[q][r] = fv * c3[q][r] + iv * gv;
                        const float h = ov * tanhC(c3[q][r]);
                        hout[(kt * 64 + m + lup) * 8 + j] = f2bf(h);
                    }
                }
            }
        } else {
            if (s >= 1) {
                // ---- back: dec2 for t=s-1 ----
                const int t = s - 1;
                const u16* hprev = h1d + (((s + 1) & 1) << 10);   // h3[t]
                const bf16x8 a3h0 = *reinterpret_cast<const bf16x8*>(hprev + lane * 8);
                const bf16x8 a3h1 = *reinterpret_cast<const bf16x8*>(hprev + (64 + lane) * 8);
                f32x4 acc4 = splat4(bias4r);
                {
                    const float4 w4 = *reinterpret_cast<const float4*>(W4hhF + col * 4);
#pragma unroll
                    for (int r = 0; r < 4; ++r) {
                        const float4 hv = *reinterpret_cast<const float4*>(bufH4 + (quad * 4 + r) * 4);
                        float sa = acc4[r];
                        sa = fmaf(w4.x, hv.x, sa);
                        sa = fmaf(w4.y, hv.y, sa);
                        sa = fmaf(w4.z, hv.z, sa);
                        sa = fmaf(w4.w, hv.w, sa);
                        acc4[r] = sa;
                    }
                }
                {
                    const bf16x8 bh0 = *reinterpret_cast<const bf16x8*>(Wih4hi + (0 * 64 + lane) * 8);
                    const bf16x8 bh1 = *reinterpret_cast<const bf16x8*>(Wih4hi + (1 * 64 + lane) * 8);
                    acc4 = MFMA(a3h0, bh0, acc4);
                    acc4 = MFMA(a3h1, bh1, acc4);
                }
                WB();
#pragma unroll
                for (int r = 0; r < 4; ++r) gbuf[(quad * 4 + r) * 16 + col] = acc4[r];
                WB();
                {   // epilogue: lane = (batch mb, unit u4)
                    const float iv = sigY(gbuf[mb * 16 + u4]);
                    const float fv = sigY(gbuf[mb * 16 + 4 + u4]);
                    const float gv = tanhY(gbuf[mb * 16 + 8 + u4]);
                    const float ov = sigY(gbuf[mb * 16 + 12 + u4]);
                    c4 = fv * c4 + iv * gv;
                    const float h = ov * tanhC(c4);
                    out[((size_t)(b0w + mb) * TT + t) * IN + u4] = h;
                    bufH4[mb * 4 + u4] = h;
                }
                WB();
            }
        }
        __syncthreads();
    }
}

extern "C" void kernel_launch(void* const* d_in, const int* in_sizes, int n_in,
                              void* d_out, int out_size, void* d_ws, size_t ws_size,
                              hipStream_t stream) {
    (void)in_sizes; (void)n_in; (void)d_ws; (void)ws_size; (void)out_size;
    hipFuncSetAttribute(reinterpret_cast<const void*>(lstm_ae),
                        hipFuncAttributeMaxDynamicSharedMemorySize, SMEM_BYTES);
    const float* xi = (const float*)d_in[0];
    const float* w1ih = (const float*)d_in[1];
    const float* w1hh = (const float*)d_in[2];
    const float* b1i = (const float*)d_in[3];
    const float* b1h = (const float*)d_in[4];
    const float* w2ih = (const float*)d_in[5];
    const float* w2hh = (const float*)d_in[6];
    const float* b2i = (const float*)d_in[7];
    const float* b2h = (const float*)d_in[8];
    const float* w3ih = (const float*)d_in[9];
    const float* w3hh = (const float*)d_in[10];
    const float* b3i = (const float*)d_in[11];
    const float* b3h = (const float*)d_in[12];
    const float* w4ih = (const float*)d_in[13];
    const float* w4hh = (const float*)d_in[14];
    const float* b4i = (const float*)d_in[15];
    const float* b4h = (const float*)d_in[16];
    float* out = (float*)d_out;

    lstm_ae<<<dim3(BATCH / BPB), dim3(BLOCKT), SMEM_BYTES, stream>>>(
        xi, w1ih, w1hh, b1i, b1h, w2ih, w2hh, b2i, b2h,
        w3ih, w3hh, b3i, b3h, w4ih, w4hh, b4i, b4h, out);
}